// Round 1
// baseline (76.863 us; speedup 1.0000x reference)
//
#include <hip/hip_runtime.h>
#include <math.h>

#define A_TOT   18675      // 83*25*9
#define N_PRE   12000
#define N_POST  2000
#define IMG_X   1333.0f
#define IMG_Y   402.0f
#define MIN_SZ  16.0f
#define NMS_T   0.7f

// ---------------- K1: decode anchors -> roi, score; zero rank ----------------
__global__ void decode_kernel(const float* __restrict__ anch,
                              const float* __restrict__ cls,
                              const float* __restrict__ pred,
                              float4* __restrict__ roi,
                              float* __restrict__ score,
                              int* __restrict__ rank) {
    int i = blockIdx.x * blockDim.x + threadIdx.x;
    if (i >= A_TOT) return;

    float ax1 = anch[4*i+0], ay1 = anch[4*i+1], ax2 = anch[4*i+2], ay2 = anch[4*i+3];
    float h_a  = __fsub_rn(ay2, ay1);
    float w_a  = __fsub_rn(ax2, ax1);
    float cy_a = __fadd_rn(ay1, __fmul_rn(0.5f, h_a));
    float cx_a = __fadd_rn(ax1, __fmul_rn(0.5f, w_a));

    float dx = pred[4*i+0], dy = pred[4*i+1], dw = pred[4*i+2], dh = pred[4*i+3];

    float cy = __fadd_rn(__fmul_rn(dy, h_a), cy_a);
    float cx = __fadd_rn(__fmul_rn(dx, w_a), cx_a);
    float h  = __fmul_rn(expf(dh), h_a);
    float w  = __fmul_rn(expf(dw), w_a);

    float hw = __fmul_rn(0.5f, w);
    float hh = __fmul_rn(0.5f, h);
    float x1 = fminf(fmaxf(__fsub_rn(cx, hw), 0.0f), IMG_X);
    float x2 = fminf(fmaxf(__fadd_rn(cx, hw), 0.0f), IMG_X);
    float y1 = fminf(fmaxf(__fsub_rn(cy, hh), 0.0f), IMG_Y);
    float y2 = fminf(fmaxf(__fadd_rn(cy, hh), 0.0f), IMG_Y);

    bool valid = (__fsub_rn(y2, y1) >= MIN_SZ) && (__fsub_rn(x2, x1) >= MIN_SZ);

    roi[i]   = make_float4(x1, y1, x2, y2);
    score[i] = valid ? cls[2*i+1] : -INFINITY;
    rank[i]  = 0;
}

// ---------------- K2: rank[i] = #{j : s_j > s_i  or (s_j == s_i and j < i)} --
__global__ void rank_tiles_kernel(const float* __restrict__ score,
                                  int* __restrict__ rank) {
    __shared__ float s_sc[256];
    const int t  = threadIdx.x;
    const int i  = blockIdx.x * 256 + t;
    const int jb = blockIdx.y * 256;

    int j = jb + t;
    s_sc[t] = (j < A_TOT) ? score[j] : __int_as_float(0x7fc00000); // NaN pad: compares false
    __syncthreads();

    float si = (i < A_TOT) ? score[i] : 0.0f;
    int cnt = 0;
#pragma unroll 16
    for (int tt = 0; tt < 256; ++tt) {
        float sj = s_sc[tt];
        int   jg = jb + tt;
        cnt += (sj > si || (sj == si && jg < i)) ? 1 : 0;
    }
    if (i < A_TOT && cnt) atomicAdd(&rank[i], cnt);
}

// ---------------- K3: scatter into score-sorted order -----------------------
__global__ void scatter_kernel(const int* __restrict__ rank,
                               const float4* __restrict__ roi,
                               float4* __restrict__ sboxes,
                               float* __restrict__ sareas) {
    int i = blockIdx.x * blockDim.x + threadIdx.x;
    if (i >= A_TOT) return;
    int r = rank[i];
    if (r < N_PRE) {
        float4 b = roi[i];
        sboxes[r] = b;
        sareas[r] = __fmul_rn(__fadd_rn(__fsub_rn(b.z, b.x), 1.0f),
                              __fadd_rn(__fsub_rn(b.w, b.y), 1.0f));
    }
}

// ---------------- K4: diagonal pair-overlap marking --------------------------
// mark[i] = OR over z in [0, N_PRE-2-i] of IoU(b[z], b[z+i+1]) >= 0.7
// One wave (64 lanes) per i; wave exclusively owns mark[i].
__global__ void nms_kernel(const float4* __restrict__ sboxes,
                           const float* __restrict__ sareas,
                           unsigned* __restrict__ mark) {
    int wid  = (blockIdx.x * blockDim.x + threadIdx.x) >> 6;
    int lane = threadIdx.x & 63;
    if (wid >= N_PRE) return;
    const int i      = wid;
    const int npairs = N_PRE - 1 - i;   // z in [0, npairs)

    bool found = false;
    for (int base = 0; base < npairs; base += 64) {
        int z = base + lane;
        bool over = false;
        if (z < npairs) {
            float4 bz = sboxes[z];
            float4 bj = sboxes[z + i + 1];
            float az = sareas[z];
            float aj = sareas[z + i + 1];
            float xx1 = fmaxf(bz.x, bj.x);
            float yy1 = fmaxf(bz.y, bj.y);
            float xx2 = fminf(bz.z, bj.z);
            float yy2 = fminf(bz.w, bj.w);
            float w = fmaxf(0.0f, __fadd_rn(__fsub_rn(xx2, xx1), 1.0f));
            float h = fmaxf(0.0f, __fadd_rn(__fsub_rn(yy2, yy1), 1.0f));
            float inter = __fmul_rn(w, h);
            float denom = __fsub_rn(__fadd_rn(az, aj), inter);
            float ovr   = __fdiv_rn(inter, denom);
            over = (ovr >= NMS_T);
        }
        if (__any(over)) { found = true; break; }
    }
    if (lane == 0) mark[i] = found ? 1u : 0u;
}

// ---------------- K5: stable compaction + output -----------------------------
__global__ void output_kernel(const unsigned* __restrict__ mark,
                              const float4* __restrict__ sboxes,
                              float* __restrict__ out) {
    __shared__ int lds[1024];
    __shared__ int s_total;
    const int t = threadIdx.x;
    const int E = 12;                 // 1024*12 = 12288 >= 12000
    const int i0 = t * E;

    bool keep[E];
    int cnt = 0;
#pragma unroll
    for (int e = 0; e < E; ++e) {
        int i = i0 + e;
        bool k = (i < N_PRE) && (mark[i] == 0u);
        keep[e] = k;
        cnt += k ? 1 : 0;
    }
    lds[t] = cnt;
    __syncthreads();
    // Hillis-Steele inclusive scan over 1024 entries
    for (int off = 1; off < 1024; off <<= 1) {
        int x = (t >= off) ? lds[t - off] : 0;
        __syncthreads();
        lds[t] += x;
        __syncthreads();
    }
    int incl = lds[t];
    int base = incl - cnt;
    if (t == 1023) s_total = incl;
    __syncthreads();
    const int total = s_total;

    int pos = base;
#pragma unroll
    for (int e = 0; e < E; ++e) {
        if (keep[e] && pos < N_POST) {
            float4 b = sboxes[i0 + e];
            out[4*pos+0] = b.x;
            out[4*pos+1] = b.y;
            out[4*pos+2] = b.z;
            out[4*pos+3] = b.w;
            out[4*N_POST + pos] = 1.0f;
        }
        pos += keep[e] ? 1 : 0;
    }
    // zero-fill slots past the kept prefix
    for (int p = t; p < N_POST; p += 1024) {
        if (p >= total) {
            out[4*p+0] = 0.0f; out[4*p+1] = 0.0f;
            out[4*p+2] = 0.0f; out[4*p+3] = 0.0f;
            out[4*N_POST + p] = 0.0f;
        }
    }
}

// ---------------- launch ------------------------------------------------------
extern "C" void kernel_launch(void* const* d_in, const int* in_sizes, int n_in,
                              void* d_out, int out_size, void* d_ws, size_t ws_size,
                              hipStream_t stream) {
    const float* anch = (const float*)d_in[0];   // (A,4)
    const float* cls  = (const float*)d_in[1];   // (1,A,2)
    const float* pred = (const float*)d_in[2];   // (1,A,4)
    float* out = (float*)d_out;                  // 8000 rois + 2000 kept

    char* ws = (char*)d_ws;
    float4*   roi    = (float4*)(ws + 0);        // A*16      = 298800
    float*    score  = (float*) (ws + 298800);   // A*4       = 74700 -> pad 373504
    float4*   sboxes = (float4*)(ws + 373504);   // 12000*16  = 192000 -> 565504
    float*    sareas = (float*) (ws + 565504);   // 12000*4   = 48000  -> 613504
    unsigned* mark   = (unsigned*)(ws + 613504); // 12000*4   = 48000  -> 661504
    int*      rank   = (int*)   (ws + 661504);   // A*4       = 74700  -> 736204

    const int TB = 256;
    const int ablk = (A_TOT + TB - 1) / TB;      // 73

    decode_kernel<<<ablk, TB, 0, stream>>>(anch, cls, pred, roi, score, rank);
    rank_tiles_kernel<<<dim3(ablk, ablk), TB, 0, stream>>>(score, rank);
    scatter_kernel<<<ablk, TB, 0, stream>>>(rank, roi, sboxes, sareas);
    nms_kernel<<<(N_PRE * 64) / TB, TB, 0, stream>>>(sboxes, sareas, mark);
    output_kernel<<<1, 1024, 0, stream>>>(mark, sboxes, out);
}

// Round 2
// 56.085 us; speedup vs baseline: 1.3705x; 1.3705x over previous
//
#include <hip/hip_runtime.h>
#include <math.h>

#define A_TOT   18675      // 83*25*9
#define N_PRE   12000
#define N_POST  2000
#define IMG_X   1333.0f
#define IMG_Y   402.0f
#define MIN_SZ  16.0f
#define NMS_T   0.7f

#define IPT     4          // i-keys per thread in rank kernel
#define JT      256        // j-tile staged in LDS
#define JCHUNK  512        // j-range per block (grid.y)

// ---------------- K1: decode anchors -> roi, key64; zero rank ----------------
__global__ void decode_kernel(const float* __restrict__ anch,
                              const float* __restrict__ cls,
                              const float* __restrict__ pred,
                              float4* __restrict__ roi,
                              unsigned long long* __restrict__ key,
                              int* __restrict__ rank) {
    int i = blockIdx.x * blockDim.x + threadIdx.x;
    if (i >= A_TOT) return;

    float ax1 = anch[4*i+0], ay1 = anch[4*i+1], ax2 = anch[4*i+2], ay2 = anch[4*i+3];
    float h_a  = __fsub_rn(ay2, ay1);
    float w_a  = __fsub_rn(ax2, ax1);
    float cy_a = __fadd_rn(ay1, __fmul_rn(0.5f, h_a));
    float cx_a = __fadd_rn(ax1, __fmul_rn(0.5f, w_a));

    float dx = pred[4*i+0], dy = pred[4*i+1], dw = pred[4*i+2], dh = pred[4*i+3];

    float cy = __fadd_rn(__fmul_rn(dy, h_a), cy_a);
    float cx = __fadd_rn(__fmul_rn(dx, w_a), cx_a);
    float h  = __fmul_rn(expf(dh), h_a);
    float w  = __fmul_rn(expf(dw), w_a);

    float hw = __fmul_rn(0.5f, w);
    float hh = __fmul_rn(0.5f, h);
    float x1 = fminf(fmaxf(__fsub_rn(cx, hw), 0.0f), IMG_X);
    float x2 = fminf(fmaxf(__fadd_rn(cx, hw), 0.0f), IMG_X);
    float y1 = fminf(fmaxf(__fsub_rn(cy, hh), 0.0f), IMG_Y);
    float y2 = fminf(fmaxf(__fadd_rn(cy, hh), 0.0f), IMG_Y);

    bool valid = (__fsub_rn(y2, y1) >= MIN_SZ) && (__fsub_rn(x2, x1) >= MIN_SZ);

    roi[i] = make_float4(x1, y1, x2, y2);

    float s = valid ? cls[2*i+1] : -INFINITY;
    // strictly-unique 64-bit key: ascending K == (descending score, ascending index)
    unsigned ub   = __float_as_uint(s);
    unsigned mask = ((unsigned)((int)ub >> 31)) | 0x80000000u;
    unsigned ord  = ub ^ mask;          // ascending float order
    unsigned kd   = ~ord;               // descending float order
    key[i]  = ((unsigned long long)kd << 32) | (unsigned)i;
    rank[i] = 0;
}

// ---------------- K2: rank[i] = #{j : K_j < K_i} ------------------------------
__global__ void rank2_kernel(const unsigned long long* __restrict__ key,
                             int* __restrict__ rank) {
    __shared__ unsigned long long kls[JT];
    const int t    = threadIdx.x;
    const int ib   = blockIdx.x * (256 * IPT);
    const int jbeg = blockIdx.y * JCHUNK;
    const int jend = min(A_TOT, jbeg + JCHUNK);

    unsigned long long ki[IPT];
    int idx[IPT];
#pragma unroll
    for (int e = 0; e < IPT; ++e) {
        int i  = ib + e * 256 + t;
        idx[e] = i;
        ki[e]  = (i < A_TOT) ? key[i] : 0ull;   // 0 never counts anything
    }
    int cnt[IPT] = {0, 0, 0, 0};

    for (int jb = jbeg; jb < jend; jb += JT) {
        int j = jb + t;
        kls[t] = (j < jend) ? key[j] : ~0ull;   // pad never counts (strict <)
        __syncthreads();
#pragma unroll 32
        for (int tt = 0; tt < JT; ++tt) {
            unsigned long long kj = kls[tt];
#pragma unroll
            for (int e = 0; e < IPT; ++e)
                cnt[e] += (kj < ki[e]) ? 1 : 0;
        }
        __syncthreads();
    }
#pragma unroll
    for (int e = 0; e < IPT; ++e)
        if (idx[e] < A_TOT && cnt[e]) atomicAdd(&rank[idx[e]], cnt[e]);
}

// ---------------- K3: scatter into score-sorted order -----------------------
__global__ void scatter_kernel(const int* __restrict__ rank,
                               const float4* __restrict__ roi,
                               float4* __restrict__ sboxes,
                               float* __restrict__ sareas) {
    int i = blockIdx.x * blockDim.x + threadIdx.x;
    if (i >= A_TOT) return;
    int r = rank[i];
    if (r < N_PRE) {
        float4 b = roi[i];
        sboxes[r] = b;
        sareas[r] = __fmul_rn(__fadd_rn(__fsub_rn(b.z, b.x), 1.0f),
                              __fadd_rn(__fsub_rn(b.w, b.y), 1.0f));
    }
}

// ---------------- K4: diagonal pair-overlap marking --------------------------
// mark[i] = OR over z in [0, N_PRE-2-i] of IoU(b[z], b[z+i+1]) >= 0.7
__global__ void nms_kernel(const float4* __restrict__ sboxes,
                           const float* __restrict__ sareas,
                           unsigned* __restrict__ mark) {
    int wid  = (blockIdx.x * blockDim.x + threadIdx.x) >> 6;
    int lane = threadIdx.x & 63;
    if (wid >= N_PRE) return;
    const int i      = wid;
    const int npairs = N_PRE - 1 - i;   // z in [0, npairs)

    bool found = false;
    for (int base = 0; base < npairs; base += 64) {
        int z = base + lane;
        bool over = false;
        if (z < npairs) {
            float4 bz = sboxes[z];
            float4 bj = sboxes[z + i + 1];
            float az = sareas[z];
            float aj = sareas[z + i + 1];
            float xx1 = fmaxf(bz.x, bj.x);
            float yy1 = fmaxf(bz.y, bj.y);
            float xx2 = fminf(bz.z, bj.z);
            float yy2 = fminf(bz.w, bj.w);
            float w = fmaxf(0.0f, __fadd_rn(__fsub_rn(xx2, xx1), 1.0f));
            float h = fmaxf(0.0f, __fadd_rn(__fsub_rn(yy2, yy1), 1.0f));
            float inter = __fmul_rn(w, h);
            float denom = __fsub_rn(__fadd_rn(az, aj), inter);
            float ovr   = __fdiv_rn(inter, denom);
            over = (ovr >= NMS_T);
        }
        if (__any(over)) { found = true; break; }
    }
    if (lane == 0) mark[i] = found ? 1u : 0u;
}

// ---------------- K5: stable compaction + output -----------------------------
__global__ void output_kernel(const unsigned* __restrict__ mark,
                              const float4* __restrict__ sboxes,
                              float* __restrict__ out) {
    __shared__ int lds[1024];
    __shared__ int s_total;
    const int t = threadIdx.x;
    const int E = 12;                 // 1024*12 = 12288 >= 12000
    const int i0 = t * E;

    bool keep[E];
    int cnt = 0;
#pragma unroll
    for (int e = 0; e < E; ++e) {
        int i = i0 + e;
        bool k = (i < N_PRE) && (mark[i] == 0u);
        keep[e] = k;
        cnt += k ? 1 : 0;
    }
    lds[t] = cnt;
    __syncthreads();
    for (int off = 1; off < 1024; off <<= 1) {
        int x = (t >= off) ? lds[t - off] : 0;
        __syncthreads();
        lds[t] += x;
        __syncthreads();
    }
    int incl = lds[t];
    int base = incl - cnt;
    if (t == 1023) s_total = incl;
    __syncthreads();
    const int total = s_total;

    int pos = base;
#pragma unroll
    for (int e = 0; e < E; ++e) {
        if (keep[e] && pos < N_POST) {
            float4 b = sboxes[i0 + e];
            out[4*pos+0] = b.x;
            out[4*pos+1] = b.y;
            out[4*pos+2] = b.z;
            out[4*pos+3] = b.w;
            out[4*N_POST + pos] = 1.0f;
        }
        pos += keep[e] ? 1 : 0;
    }
    for (int p = t; p < N_POST; p += 1024) {
        if (p >= total) {
            out[4*p+0] = 0.0f; out[4*p+1] = 0.0f;
            out[4*p+2] = 0.0f; out[4*p+3] = 0.0f;
            out[4*N_POST + p] = 0.0f;
        }
    }
}

// ---------------- launch ------------------------------------------------------
extern "C" void kernel_launch(void* const* d_in, const int* in_sizes, int n_in,
                              void* d_out, int out_size, void* d_ws, size_t ws_size,
                              hipStream_t stream) {
    const float* anch = (const float*)d_in[0];   // (A,4)
    const float* cls  = (const float*)d_in[1];   // (1,A,2)
    const float* pred = (const float*)d_in[2];   // (1,A,4)
    float* out = (float*)d_out;                  // 8000 rois + 2000 kept

    char* ws = (char*)d_ws;
    // roi:    [0, 298800)
    // rank:   [298800, 373500)
    // key:    [373504, 522904)   -- dead after rank2
    // sboxes: [373504, 565504)   -- aliases key (written after key is dead)
    // sareas: [565504, 613504)
    // mark:   [613504, 661504)
    float4*             roi    = (float4*)(ws + 0);
    int*                rank   = (int*)   (ws + 298800);
    unsigned long long* key    = (unsigned long long*)(ws + 373504);
    float4*             sboxes = (float4*)(ws + 373504);
    float*              sareas = (float*) (ws + 565504);
    unsigned*           mark   = (unsigned*)(ws + 613504);

    const int TB = 256;
    const int ablk = (A_TOT + TB - 1) / TB;               // 73
    const int nIblk = (A_TOT + 256*IPT - 1) / (256*IPT);  // 19
    const int njc   = (A_TOT + JCHUNK - 1) / JCHUNK;      // 37

    decode_kernel<<<ablk, TB, 0, stream>>>(anch, cls, pred, roi, key, rank);
    rank2_kernel<<<dim3(nIblk, njc), TB, 0, stream>>>(key, rank);
    scatter_kernel<<<ablk, TB, 0, stream>>>(rank, roi, sboxes, sareas);
    nms_kernel<<<(N_PRE * 64) / TB, TB, 0, stream>>>(sboxes, sareas, mark);
    output_kernel<<<1, 1024, 0, stream>>>(mark, sboxes, out);
}